// Round 11
// baseline (175.295 us; speedup 1.0000x reference)
//
#include <hip/hip_runtime.h>
#include <hip/hip_bf16.h>
#include <math.h>

typedef __hip_bfloat16 bf16;
using f32x4  = __attribute__((ext_vector_type(4))) float;
using f32x2  = __attribute__((ext_vector_type(2))) float;
using bf16x8 = __attribute__((ext_vector_type(8))) short;
using f16x2  = __attribute__((ext_vector_type(2))) _Float16;

constexpr int BS = 2, NQ = 22223, MROWS = 44446;
constexpr int LH[4] = {100, 50, 25, 13};
constexpr int LW[4] = {167, 84, 42, 21};
constexpr int LSTART[4] = {0, 16700, 20900, 21950};
// Padded levels: +1 left/top, +2 right/bottom (Wp=W+3, Hp=H+3)
constexpr int PLW[4] = {170, 87, 45, 24};
constexpr int PLSTART[4] = {0, 17510, 22121, 23381};
constexpr int PTOT = 23765;

constexpr int BM = 128, BK = 32;
constexpr int LDT = 40;               // LDS row stride (bf16): 80B
constexpr int GX = (MROWS + BM - 1) / BM;   // 348

// ---------------------------------------------------------------------------
__global__ __launch_bounds__(256) void prep_weights(
    const float* __restrict__ W_vp, const float* __restrict__ W_so,
    const float* __restrict__ W_aw, const float* __restrict__ W_op,
    const float* __restrict__ b_so, const float* __restrict__ b_aw,
    bf16* __restrict__ Wt_vp, bf16* __restrict__ Wt_cat,
    bf16* __restrict__ Wt_op, float* __restrict__ bcat)
{
    int i = blockIdx.x * 256 + threadIdx.x;
    if (i < 256 * 256) {
        int n = i >> 8, k = i & 255;
        Wt_vp[i] = __float2bfloat16(W_vp[k * 256 + n]);
        Wt_op[i] = __float2bfloat16(W_op[k * 256 + n]);
    }
    if (i < 384 * 256) {
        int n = i >> 8, k = i & 255;
        float v = (n < 256) ? W_so[k * 256 + n] : W_aw[k * 128 + (n - 256)];
        Wt_cat[i] = __float2bfloat16(v);
    }
    if (i < 384) bcat[i] = (i < 256) ? b_so[i] : b_aw[i - 256];
}

// Map batch-local value pixel -> level-local padded pixel index (+1,+1 offset)
__device__ inline int pad_base_idx(int pix) {
    if (pix < LSTART[1])      { int y = pix / 167;                  int x = pix - y * 167;                return PLSTART[0] + (y + 1) * 170 + (x + 1); }
    else if (pix < LSTART[2]) { int rel = pix - LSTART[1]; int y = rel / 84; int x = rel - y * 84;        return PLSTART[1] + (y + 1) * 87  + (x + 1); }
    else if (pix < LSTART[3]) { int rel = pix - LSTART[2]; int y = rel / 42; int x = rel - y * 42;        return PLSTART[2] + (y + 1) * 45  + (x + 1); }
    else                      { int rel = pix - LSTART[3]; int y = rel / 21; int x = rel - y * 21;        return PLSTART[3] + (y + 1) * 24  + (x + 1); }
}

// ---------------------------------------------------------------------------
// Shared MFMA tile core: acc[4][4] (64x64 per wave) over K=256, BK=32.
// ---------------------------------------------------------------------------
template<bool A_BF16>
__device__ __forceinline__ void mfma_core(
    const void* __restrict__ Av, int lda, const bf16* __restrict__ Wt,
    int row0, int bn0, int M, bf16* As, bf16* Bs, f32x4 (&acc)[4][4])
{
    const int tid = threadIdx.x;
    const int lane = tid & 63;
    const int wv = tid >> 6;
    const int wm = (wv >> 1) * 64, wn = (wv & 1) * 64;
    const int l15 = lane & 15, l4 = lane >> 4;

#pragma unroll
    for (int m = 0; m < 4; ++m)
#pragma unroll
        for (int n = 0; n < 4; ++n) { acc[m][n][0]=0.f; acc[m][n][1]=0.f; acc[m][n][2]=0.f; acc[m][n][3]=0.f; }

    for (int k0 = 0; k0 < 256; k0 += BK) {
        __syncthreads();
#pragma unroll
        for (int t = 0; t < 2; ++t) {
            int idx = tid + t * 256;
            int r = idx >> 2, s = idx & 3;
            {
                int grow = row0 + r; if (grow >= M) grow = M - 1;
                bf16 tmp[8];
                if constexpr (A_BF16) {
                    const bf16* ap = (const bf16*)Av + (size_t)grow * lda + (k0 + s * 8);
                    *(uint4*)tmp = *(const uint4*)ap;
                } else {
                    const float* ap = (const float*)Av + (size_t)grow * lda + (k0 + s * 8);
                    f32x4 v0 = *(const f32x4*)ap;
                    f32x4 v1 = *(const f32x4*)(ap + 4);
#pragma unroll
                    for (int j = 0; j < 4; ++j) tmp[j] = __float2bfloat16(v0[j]);
#pragma unroll
                    for (int j = 0; j < 4; ++j) tmp[4 + j] = __float2bfloat16(v1[j]);
                }
                *(uint4*)&As[r * LDT + s * 8] = *(const uint4*)tmp;
            }
            *(uint4*)&Bs[r * LDT + s * 8] =
                *(const uint4*)(Wt + (size_t)(bn0 + r) * 256 + (k0 + s * 8));
        }
        __syncthreads();

        bf16x8 af[4], bfr[4];
#pragma unroll
        for (int m = 0; m < 4; ++m)
            af[m] = *(const bf16x8*)&As[(wm + m * 16 + l15) * LDT + l4 * 8];
#pragma unroll
        for (int n = 0; n < 4; ++n)
            bfr[n] = *(const bf16x8*)&Bs[(wn + n * 16 + l15) * LDT + l4 * 8];
#pragma unroll
        for (int m = 0; m < 4; ++m)
#pragma unroll
            for (int n = 0; n < 4; ++n)
                acc[m][n] = __builtin_amdgcn_mfma_f32_16x16x32_bf16(af[m], bfr[n], acc[m][n], 0, 0, 0);
    }
}

// ---------------------------------------------------------------------------
// Fused producer GEMM: 5 N-slices per row-panel (3 offawl bf16 + 2 vproj fp16
// head-major scatter), slice-fastest linearization + bijective XCD swizzle.
// vproj layout: [head][batch][padded_pixel][32ch] fp16 (pixel stride 64B).
// ---------------------------------------------------------------------------
__global__ __launch_bounds__(256) void gemm_producer(
    const float* __restrict__ query, const float* __restrict__ value,
    const bf16* __restrict__ Wt_cat, const bf16* __restrict__ Wt_vp,
    const float* __restrict__ bcat, const float* __restrict__ bvp,
    bf16* __restrict__ offawl, _Float16* __restrict__ vproj)
{
    __shared__ bf16 As[BM * LDT];
    __shared__ bf16 Bs[BM * LDT];

    constexpr int NWG = GX * 5;                 // 1740
    constexpr int QXW = NWG / 8, RXW = NWG % 8; // 217, 4
    int orig = blockIdx.x;
    int xcd = orig & 7, seq = orig >> 3;
    int swz = (xcd < RXW ? xcd * (QXW + 1) : RXW * (QXW + 1) + (xcd - RXW) * QXW) + seq;
    int slice = swz % 5;
    int row0 = (swz / 5) * BM;

    const bool isOff = slice < 3;
    const void* A = isOff ? (const void*)query : (const void*)value;
    const bf16* Wt = isOff ? Wt_cat : Wt_vp;
    const float* bias = isOff ? bcat : bvp;
    int bn0 = isOff ? slice * 128 : (slice - 3) * 128;

    f32x4 acc[4][4];
    mfma_core<false>(A, 256, Wt, row0, bn0, MROWS, As, Bs, acc);

    const int lane = threadIdx.x & 63;
    const int wv = threadIdx.x >> 6;
    const int wm = (wv >> 1) * 64, wn = (wv & 1) * 64;
    const int l15 = lane & 15, l4 = lane >> 4;

    if (isOff) {
#pragma unroll
        for (int m = 0; m < 4; ++m)
#pragma unroll
            for (int j = 0; j < 4; ++j) {
                int r = row0 + wm + m * 16 + l4 * 4 + j;
                if (r < MROWS) {
                    bf16* orow = offawl + (size_t)r * 384;
#pragma unroll
                    for (int n = 0; n < 4; ++n) {
                        int fcol = bn0 + wn + n * 16 + l15;
                        orow[fcol] = __float2bfloat16(acc[m][n][j] + bias[fcol]);
                    }
                }
            }
    } else {
#pragma unroll
        for (int m = 0; m < 4; ++m)
#pragma unroll
            for (int j = 0; j < 4; ++j) {
                int r = row0 + wm + m * 16 + l4 * 4 + j;
                if (r < MROWS) {
                    int bb = (r >= NQ) ? 1 : 0;
                    int pb = pad_base_idx(r - bb * NQ);
#pragma unroll
                    for (int n = 0; n < 4; ++n) {
                        int fcol = bn0 + wn + n * 16 + l15;
                        int hh = fcol >> 5, cc = fcol & 31;
                        vproj[((size_t)(hh * 2 + bb) * PTOT + pb) * 32 + cc] =
                            (_Float16)(acc[m][n][j] + bias[fcol]);
                    }
                }
            }
    }
}

// ---------------------------------------------------------------------------
// Output GEMM: out = msda(bf16, ld 384) @ W_op^T + b_op + query.
// ---------------------------------------------------------------------------
__global__ __launch_bounds__(256) void gemm_out(
    const bf16* __restrict__ msda, const bf16* __restrict__ Wt_op,
    const float* __restrict__ b_op, const float* __restrict__ query,
    float* __restrict__ out)
{
    __shared__ bf16 As[BM * LDT];
    __shared__ bf16 Bs[BM * LDT];

    constexpr int NWG = GX * 2;  // 696
    int orig = blockIdx.x;
    int swz = (orig & 7) * (NWG / 8) + (orig >> 3);
    int bn0 = (swz & 1) * 128;
    int row0 = (swz >> 1) * BM;

    f32x4 acc[4][4];
    mfma_core<true>(msda, 384, Wt_op, row0, bn0, MROWS, As, Bs, acc);

    const int lane = threadIdx.x & 63;
    const int wv = threadIdx.x >> 6;
    const int wm = (wv >> 1) * 64, wn = (wv & 1) * 64;
    const int l15 = lane & 15, l4 = lane >> 4;

#pragma unroll
    for (int m = 0; m < 4; ++m)
#pragma unroll
        for (int j = 0; j < 4; ++j) {
            int r = row0 + wm + m * 16 + l4 * 4 + j;
            if (r < MROWS) {
#pragma unroll
                for (int n = 0; n < 4; ++n) {
                    int fcol = bn0 + wn + n * 16 + l15;
                    out[(size_t)r * 256 + fcol] =
                        acc[m][n][j] + b_op[fcol] + query[(size_t)r * 256 + fcol];
                }
            }
        }
}

// ---------------------------------------------------------------------------
// MSDA sampling v11 = v10 with waves_per_eu(2, 8): same allocator budget
// (min 2 -> VGPR 72 codegen with 16-deep load batches preserved), but the
// runtime wave cap raised from 4 to 8 per EU -> occupancy can reach the
// VGPR-limited ~7 waves/EU and hide gather latency via TLP * ILP.
// ---------------------------------------------------------------------------
__device__ inline f32x2 bfpair(unsigned u) {
    f32x2 r;
    r.x = __uint_as_float(u << 16);
    r.y = __uint_as_float(u & 0xffff0000u);
    return r;
}

__global__ __launch_bounds__(256)
__attribute__((amdgpu_waves_per_eu(2, 8)))
void msda_sample11(
    const _Float16* __restrict__ vproj,  // [head][batch][ppix][32] fp16
    const bf16* __restrict__ offawl,     // [MROWS][384] bf16
    const float* __restrict__ refp,
    bf16* __restrict__ msda_out)         // aliases offawl rows (stride 384)
{
    __shared__ uint2 sOA[8][128];        // 8 rows x 1024B (payload 768B)
    __shared__ float sRef[8][8];

    // bijective XCD swizzle
    constexpr int NBLK = (MROWS + 7) / 8;        // 5556
    constexpr int QX = NBLK / 8, RX = NBLK % 8;  // 694, 4
    const int orig = blockIdx.x;
    const int xcd = orig & 7, seq = orig >> 3;
    const int blk = (xcd < RX ? xcd * (QX + 1) : RX * (QX + 1) + (xcd - RX) * QX) + seq;
    const int q0 = blk * 8;

    const int tid = threadIdx.x;

#pragma unroll
    for (int k = 0; k < 4; ++k) {
        int idx = tid + k * 256;
        int row = idx >> 7, e = idx & 127;
        if (e < 96) {
            int grow = min(q0 + row, MROWS - 1);
            sOA[row][e] = *((const uint2*)(offawl + (size_t)grow * 384) + e);
        }
    }
    if (tid < 64) {
        int row = tid >> 3, er = tid & 7;
        int grow = min(q0 + row, MROWS - 1);
        sRef[row][er] = refp[(size_t)grow * 8 + er];
    }
    __syncthreads();

    const int w = tid >> 6;
    const int lane = tid & 63;
    const int qs = lane >> 5;
    const int h = (lane >> 2) & 7;
    const int s = lane & 3;
    const int qrow = w * 2 + qs;
    int q = q0 + qrow;
    const bool alive = q < MROWS;
    if (!alive) q = MROWS - 1;
    const int b = (q >= NQ) ? 1 : 0;

    const char* rowp = (const char*)&sOA[qrow][0];
    unsigned off16[16];
    {
        uint4 o0 = *(const uint4*)(rowp + h * 64);
        uint4 o1 = *(const uint4*)(rowp + h * 64 + 16);
        uint4 o2 = *(const uint4*)(rowp + h * 64 + 32);
        uint4 o3 = *(const uint4*)(rowp + h * 64 + 48);
        off16[0]=o0.x; off16[1]=o0.y; off16[2]=o0.z; off16[3]=o0.w;
        off16[4]=o1.x; off16[5]=o1.y; off16[6]=o1.z; off16[7]=o1.w;
        off16[8]=o2.x; off16[9]=o2.y; off16[10]=o2.z; off16[11]=o2.w;
        off16[12]=o3.x; off16[13]=o3.y; off16[14]=o3.z; off16[15]=o3.w;
    }

    float aw[16];
    {
        uint4 g0 = *(const uint4*)(rowp + 512 + h * 32);
        uint4 g1 = *(const uint4*)(rowp + 512 + h * 32 + 16);
        unsigned gu[8] = {g0.x,g0.y,g0.z,g0.w,g1.x,g1.y,g1.z,g1.w};
        float lg[16];
#pragma unroll
        for (int i = 0; i < 8; ++i) {
            f32x2 p = bfpair(gu[i]);
            lg[2*i] = p.x; lg[2*i+1] = p.y;
        }
        float mx = lg[0];
#pragma unroll
        for (int i = 1; i < 16; ++i) mx = fmaxf(mx, lg[i]);
        float ssum = 0.f;
#pragma unroll
        for (int i = 0; i < 16; ++i) { aw[i] = __expf(lg[i] - mx); ssum += aw[i]; }
        float inv = 1.f / ssum;
#pragma unroll
        for (int i = 0; i < 16; ++i) aw[i] *= inv;
    }

    f16x2 acc0 = {0, 0}, acc1 = {0, 0}, acc2 = {0, 0}, acc3 = {0, 0};

#pragma unroll
    for (int l = 0; l < 4; ++l) {
        const int W = LW[l], H = LH[l], Wp = PLW[l];
        const float xb = sRef[qrow][l * 2 + 0] * (float)W + 0.5f;   // pad-coord base
        const float yb = sRef[qrow][l * 2 + 1] * (float)H + 0.5f;
        // head-major: pixel stride is 32 fp16 (64B)
        const _Float16* vl = vproj + ((size_t)(h * 2 + b) * PTOT + PLSTART[l]) * 32 + s * 8;

        // Phase 1: addresses + packed fp16 weights for all 4 taps of this level
        const _Float16* pp[4];
        f16x2 hw[4][4];
#pragma unroll
        for (int p = 0; p < 4; ++p) {
            const int t = l * 4 + p;
            f32x2 o2 = bfpair(off16[t]);
            float x = fminf(fmaxf(xb + o2.x, 0.f), (float)(W + 1));
            float y = fminf(fmaxf(yb + o2.y, 0.f), (float)(H + 1));
            float x0f = floorf(x), y0f = floorf(y);
            float lx = x - x0f, ly = y - y0f;
            int x0 = (int)x0f, y0 = (int)y0f;
            pp[p] = vl + (size_t)((y0 * Wp + x0) * 32);
            float aww = aw[t];
            float wx0 = 1.f - lx;
            float wy0 = (1.f - ly) * aww, wy1 = ly * aww;
            _Float16 h00 = (_Float16)(wx0 * wy0), h01 = (_Float16)(lx * wy0);
            _Float16 h10 = (_Float16)(wx0 * wy1), h11 = (_Float16)(lx * wy1);
            hw[p][0] = f16x2{h00, h00}; hw[p][1] = f16x2{h01, h01};
            hw[p][2] = f16x2{h10, h10}; hw[p][3] = f16x2{h11, h11};
        }

        // Phase 2: issue all 16 gathers (x-pairs are contiguous 128B regions)
        uint4 c[4][4];
#pragma unroll
        for (int p = 0; p < 4; ++p) {
            c[p][0] = *(const uint4*)(pp[p]);
            c[p][1] = *(const uint4*)(pp[p] + 32);
            c[p][2] = *(const uint4*)(pp[p] + Wp * 32);
            c[p][3] = *(const uint4*)(pp[p] + Wp * 32 + 32);
        }

        // Phase 3: packed fp16 FMAs
#pragma unroll
        for (int p = 0; p < 4; ++p)
#pragma unroll
            for (int cc = 0; cc < 4; ++cc) {
                acc0 += __builtin_bit_cast(f16x2, c[p][cc].x) * hw[p][cc];
                acc1 += __builtin_bit_cast(f16x2, c[p][cc].y) * hw[p][cc];
                acc2 += __builtin_bit_cast(f16x2, c[p][cc].z) * hw[p][cc];
                acc3 += __builtin_bit_cast(f16x2, c[p][cc].w) * hw[p][cc];
            }
    }

    if (alive) {
        bf16 ob[8];
        ob[0] = __float2bfloat16((float)acc0[0]);
        ob[1] = __float2bfloat16((float)acc0[1]);
        ob[2] = __float2bfloat16((float)acc1[0]);
        ob[3] = __float2bfloat16((float)acc1[1]);
        ob[4] = __float2bfloat16((float)acc2[0]);
        ob[5] = __float2bfloat16((float)acc2[1]);
        ob[6] = __float2bfloat16((float)acc3[0]);
        ob[7] = __float2bfloat16((float)acc3[1]);
        *(uint4*)(msda_out + (size_t)q * 384 + h * 32 + s * 8) = *(const uint4*)ob;
    }
}

// ---------------------------------------------------------------------------
extern "C" void kernel_launch(void* const* d_in, const int* in_sizes, int n_in,
                              void* d_out, int out_size, void* d_ws, size_t ws_size,
                              hipStream_t stream) {
    const float* query = (const float*)d_in[0];
    const float* value = (const float*)d_in[1];
    const float* refp  = (const float*)d_in[2];
    const float* W_so  = (const float*)d_in[3];
    const float* b_so  = (const float*)d_in[4];
    const float* W_aw  = (const float*)d_in[5];
    const float* b_aw  = (const float*)d_in[6];
    const float* W_vp  = (const float*)d_in[7];
    const float* b_vp  = (const float*)d_in[8];
    const float* W_op  = (const float*)d_in[9];
    const float* b_op  = (const float*)d_in[10];
    float* out = (float*)d_out;

    // Workspace:
    //   offawl : bf16 MROWS*384 (34.1 MB) [off|awl]; msda aliased over rows
    //   vproj  : fp16 16*PTOT*32 (24.3 MB) head-major zero-padded layout
    //   weights: Wt_cat 384*256, Wt_vp/Wt_op 256*256 bf16, bcat 384 f32
    bf16*     d_offawl = (bf16*)d_ws;
    _Float16* d_vproj  = (_Float16*)(d_offawl + (size_t)MROWS * 384);
    bf16*     d_wtcat  = (bf16*)(d_vproj + (size_t)16 * PTOT * 32);
    bf16*     d_wtvp   = d_wtcat + 384 * 256;
    bf16*     d_wtop   = d_wtvp + 256 * 256;
    float*    d_bcat   = (float*)(d_wtop + 256 * 256);

    prep_weights<<<384, 256, 0, stream>>>(W_vp, W_so, W_aw, W_op, b_so, b_aw,
                                          d_wtvp, d_wtcat, d_wtop, d_bcat);
    hipMemsetAsync(d_vproj, 0, (size_t)16 * PTOT * 32 * sizeof(_Float16), stream);

    gemm_producer<<<GX * 5, 256, 0, stream>>>(
        query, value, d_wtcat, d_wtvp, d_bcat, b_vp, d_offawl, d_vproj);

    msda_sample11<<<(MROWS + 7) / 8, 256, 0, stream>>>(
        d_vproj, d_offawl, refp, d_offawl);

    gemm_out<<<GX * 2, 256, 0, stream>>>(d_offawl, d_wtop, b_op, query, out);
}

// Round 12
// 170.314 us; speedup vs baseline: 1.0293x; 1.0293x over previous
//
#include <hip/hip_runtime.h>
#include <hip/hip_bf16.h>
#include <math.h>

typedef __hip_bfloat16 bf16;
using f32x4  = __attribute__((ext_vector_type(4))) float;
using f32x2  = __attribute__((ext_vector_type(2))) float;
using bf16x8 = __attribute__((ext_vector_type(8))) short;
using f16x2  = __attribute__((ext_vector_type(2))) _Float16;

constexpr int BS = 2, NQ = 22223, MROWS = 44446;
constexpr int LH[4] = {100, 50, 25, 13};
constexpr int LW[4] = {167, 84, 42, 21};
constexpr int LSTART[4] = {0, 16700, 20900, 21950};
// Padded levels: +1 left/top, +2 right/bottom (Wp=W+3, Hp=H+3)
constexpr int PLW[4] = {170, 87, 45, 24};
constexpr int PLSTART[4] = {0, 17510, 22121, 23381};
constexpr int PTOT = 23765;

constexpr int BM = 128, BK = 32;
constexpr int LDT = 40;               // LDS row stride (bf16): 80B
constexpr int GX = (MROWS + BM - 1) / BM;   // 348

// ---------------------------------------------------------------------------
__global__ __launch_bounds__(256) void prep_weights(
    const float* __restrict__ W_vp, const float* __restrict__ W_so,
    const float* __restrict__ W_aw, const float* __restrict__ W_op,
    const float* __restrict__ b_so, const float* __restrict__ b_aw,
    bf16* __restrict__ Wt_vp, bf16* __restrict__ Wt_cat,
    bf16* __restrict__ Wt_op, float* __restrict__ bcat)
{
    int i = blockIdx.x * 256 + threadIdx.x;
    if (i < 256 * 256) {
        int n = i >> 8, k = i & 255;
        Wt_vp[i] = __float2bfloat16(W_vp[k * 256 + n]);
        Wt_op[i] = __float2bfloat16(W_op[k * 256 + n]);
    }
    if (i < 384 * 256) {
        int n = i >> 8, k = i & 255;
        float v = (n < 256) ? W_so[k * 256 + n] : W_aw[k * 128 + (n - 256)];
        Wt_cat[i] = __float2bfloat16(v);
    }
    if (i < 384) bcat[i] = (i < 256) ? b_so[i] : b_aw[i - 256];
}

// Map batch-local value pixel -> level-local padded pixel index (+1,+1 offset)
__device__ inline int pad_base_idx(int pix) {
    if (pix < LSTART[1])      { int y = pix / 167;                  int x = pix - y * 167;                return PLSTART[0] + (y + 1) * 170 + (x + 1); }
    else if (pix < LSTART[2]) { int rel = pix - LSTART[1]; int y = rel / 84; int x = rel - y * 84;        return PLSTART[1] + (y + 1) * 87  + (x + 1); }
    else if (pix < LSTART[3]) { int rel = pix - LSTART[2]; int y = rel / 42; int x = rel - y * 42;        return PLSTART[2] + (y + 1) * 45  + (x + 1); }
    else                      { int rel = pix - LSTART[3]; int y = rel / 21; int x = rel - y * 21;        return PLSTART[3] + (y + 1) * 24  + (x + 1); }
}

// ---------------------------------------------------------------------------
// Shared MFMA tile core: acc[4][4] (64x64 per wave) over K=256, BK=32.
// ---------------------------------------------------------------------------
template<bool A_BF16>
__device__ __forceinline__ void mfma_core(
    const void* __restrict__ Av, int lda, const bf16* __restrict__ Wt,
    int row0, int bn0, int M, bf16* As, bf16* Bs, f32x4 (&acc)[4][4])
{
    const int tid = threadIdx.x;
    const int lane = tid & 63;
    const int wv = tid >> 6;
    const int wm = (wv >> 1) * 64, wn = (wv & 1) * 64;
    const int l15 = lane & 15, l4 = lane >> 4;

#pragma unroll
    for (int m = 0; m < 4; ++m)
#pragma unroll
        for (int n = 0; n < 4; ++n) { acc[m][n][0]=0.f; acc[m][n][1]=0.f; acc[m][n][2]=0.f; acc[m][n][3]=0.f; }

    for (int k0 = 0; k0 < 256; k0 += BK) {
        __syncthreads();
#pragma unroll
        for (int t = 0; t < 2; ++t) {
            int idx = tid + t * 256;
            int r = idx >> 2, s = idx & 3;
            {
                int grow = row0 + r; if (grow >= M) grow = M - 1;
                bf16 tmp[8];
                if constexpr (A_BF16) {
                    const bf16* ap = (const bf16*)Av + (size_t)grow * lda + (k0 + s * 8);
                    *(uint4*)tmp = *(const uint4*)ap;
                } else {
                    const float* ap = (const float*)Av + (size_t)grow * lda + (k0 + s * 8);
                    f32x4 v0 = *(const f32x4*)ap;
                    f32x4 v1 = *(const f32x4*)(ap + 4);
#pragma unroll
                    for (int j = 0; j < 4; ++j) tmp[j] = __float2bfloat16(v0[j]);
#pragma unroll
                    for (int j = 0; j < 4; ++j) tmp[4 + j] = __float2bfloat16(v1[j]);
                }
                *(uint4*)&As[r * LDT + s * 8] = *(const uint4*)tmp;
            }
            *(uint4*)&Bs[r * LDT + s * 8] =
                *(const uint4*)(Wt + (size_t)(bn0 + r) * 256 + (k0 + s * 8));
        }
        __syncthreads();

        bf16x8 af[4], bfr[4];
#pragma unroll
        for (int m = 0; m < 4; ++m)
            af[m] = *(const bf16x8*)&As[(wm + m * 16 + l15) * LDT + l4 * 8];
#pragma unroll
        for (int n = 0; n < 4; ++n)
            bfr[n] = *(const bf16x8*)&Bs[(wn + n * 16 + l15) * LDT + l4 * 8];
#pragma unroll
        for (int m = 0; m < 4; ++m)
#pragma unroll
            for (int n = 0; n < 4; ++n)
                acc[m][n] = __builtin_amdgcn_mfma_f32_16x16x32_bf16(af[m], bfr[n], acc[m][n], 0, 0, 0);
    }
}

// ---------------------------------------------------------------------------
// Fused producer GEMM: 5 N-slices per row-panel (3 offawl bf16 + 2 vproj fp16
// head-major scatter), slice-fastest linearization + bijective XCD swizzle.
// vproj layout: [head][batch][padded_pixel][32ch] fp16 (pixel stride 64B).
// ---------------------------------------------------------------------------
__global__ __launch_bounds__(256) void gemm_producer(
    const float* __restrict__ query, const float* __restrict__ value,
    const bf16* __restrict__ Wt_cat, const bf16* __restrict__ Wt_vp,
    const float* __restrict__ bcat, const float* __restrict__ bvp,
    bf16* __restrict__ offawl, _Float16* __restrict__ vproj)
{
    __shared__ bf16 As[BM * LDT];
    __shared__ bf16 Bs[BM * LDT];

    constexpr int NWG = GX * 5;                 // 1740
    constexpr int QXW = NWG / 8, RXW = NWG % 8; // 217, 4
    int orig = blockIdx.x;
    int xcd = orig & 7, seq = orig >> 3;
    int swz = (xcd < RXW ? xcd * (QXW + 1) : RXW * (QXW + 1) + (xcd - RXW) * QXW) + seq;
    int slice = swz % 5;
    int row0 = (swz / 5) * BM;

    const bool isOff = slice < 3;
    const void* A = isOff ? (const void*)query : (const void*)value;
    const bf16* Wt = isOff ? Wt_cat : Wt_vp;
    const float* bias = isOff ? bcat : bvp;
    int bn0 = isOff ? slice * 128 : (slice - 3) * 128;

    f32x4 acc[4][4];
    mfma_core<false>(A, 256, Wt, row0, bn0, MROWS, As, Bs, acc);

    const int lane = threadIdx.x & 63;
    const int wv = threadIdx.x >> 6;
    const int wm = (wv >> 1) * 64, wn = (wv & 1) * 64;
    const int l15 = lane & 15, l4 = lane >> 4;

    if (isOff) {
#pragma unroll
        for (int m = 0; m < 4; ++m)
#pragma unroll
            for (int j = 0; j < 4; ++j) {
                int r = row0 + wm + m * 16 + l4 * 4 + j;
                if (r < MROWS) {
                    bf16* orow = offawl + (size_t)r * 384;
#pragma unroll
                    for (int n = 0; n < 4; ++n) {
                        int fcol = bn0 + wn + n * 16 + l15;
                        orow[fcol] = __float2bfloat16(acc[m][n][j] + bias[fcol]);
                    }
                }
            }
    } else {
#pragma unroll
        for (int m = 0; m < 4; ++m)
#pragma unroll
            for (int j = 0; j < 4; ++j) {
                int r = row0 + wm + m * 16 + l4 * 4 + j;
                if (r < MROWS) {
                    int bb = (r >= NQ) ? 1 : 0;
                    int pb = pad_base_idx(r - bb * NQ);
#pragma unroll
                    for (int n = 0; n < 4; ++n) {
                        int fcol = bn0 + wn + n * 16 + l15;
                        int hh = fcol >> 5, cc = fcol & 31;
                        vproj[((size_t)(hh * 2 + bb) * PTOT + pb) * 32 + cc] =
                            (_Float16)(acc[m][n][j] + bias[fcol]);
                    }
                }
            }
    }
}

// ---------------------------------------------------------------------------
// Output GEMM: out = msda(bf16, ld 384) @ W_op^T + b_op + query.
// ---------------------------------------------------------------------------
__global__ __launch_bounds__(256) void gemm_out(
    const bf16* __restrict__ msda, const bf16* __restrict__ Wt_op,
    const float* __restrict__ b_op, const float* __restrict__ query,
    float* __restrict__ out)
{
    __shared__ bf16 As[BM * LDT];
    __shared__ bf16 Bs[BM * LDT];

    constexpr int NWG = GX * 2;  // 696
    int orig = blockIdx.x;
    int swz = (orig & 7) * (NWG / 8) + (orig >> 3);
    int bn0 = (swz & 1) * 128;
    int row0 = (swz >> 1) * BM;

    f32x4 acc[4][4];
    mfma_core<true>(msda, 384, Wt_op, row0, bn0, MROWS, As, Bs, acc);

    const int lane = threadIdx.x & 63;
    const int wv = threadIdx.x >> 6;
    const int wm = (wv >> 1) * 64, wn = (wv & 1) * 64;
    const int l15 = lane & 15, l4 = lane >> 4;

#pragma unroll
    for (int m = 0; m < 4; ++m)
#pragma unroll
        for (int j = 0; j < 4; ++j) {
            int r = row0 + wm + m * 16 + l4 * 4 + j;
            if (r < MROWS) {
#pragma unroll
                for (int n = 0; n < 4; ++n) {
                    int fcol = bn0 + wn + n * 16 + l15;
                    out[(size_t)r * 256 + fcol] =
                        acc[m][n][j] + b_op[fcol] + query[(size_t)r * 256 + fcol];
                }
            }
        }
}

// ---------------------------------------------------------------------------
// MSDA sampling v12 = v10 with waves_per_eu(4, 4): max=4 keeps the compiler's
// codegen target at 4 waves/EU (VGPR budget 128 -> the 72-VGPR 16-deep load
// batches survive, per R10/R11 evidence that codegen follows MAX), while
// min=4 raises the occupancy floor from the measured ~2.3 waves/EU toward 4.
// ---------------------------------------------------------------------------
__device__ inline f32x2 bfpair(unsigned u) {
    f32x2 r;
    r.x = __uint_as_float(u << 16);
    r.y = __uint_as_float(u & 0xffff0000u);
    return r;
}

__global__ __launch_bounds__(256)
__attribute__((amdgpu_waves_per_eu(4, 4)))
void msda_sample12(
    const _Float16* __restrict__ vproj,  // [head][batch][ppix][32] fp16
    const bf16* __restrict__ offawl,     // [MROWS][384] bf16
    const float* __restrict__ refp,
    bf16* __restrict__ msda_out)         // aliases offawl rows (stride 384)
{
    __shared__ uint2 sOA[8][128];        // 8 rows x 1024B (payload 768B)
    __shared__ float sRef[8][8];

    // bijective XCD swizzle
    constexpr int NBLK = (MROWS + 7) / 8;        // 5556
    constexpr int QX = NBLK / 8, RX = NBLK % 8;  // 694, 4
    const int orig = blockIdx.x;
    const int xcd = orig & 7, seq = orig >> 3;
    const int blk = (xcd < RX ? xcd * (QX + 1) : RX * (QX + 1) + (xcd - RX) * QX) + seq;
    const int q0 = blk * 8;

    const int tid = threadIdx.x;

#pragma unroll
    for (int k = 0; k < 4; ++k) {
        int idx = tid + k * 256;
        int row = idx >> 7, e = idx & 127;
        if (e < 96) {
            int grow = min(q0 + row, MROWS - 1);
            sOA[row][e] = *((const uint2*)(offawl + (size_t)grow * 384) + e);
        }
    }
    if (tid < 64) {
        int row = tid >> 3, er = tid & 7;
        int grow = min(q0 + row, MROWS - 1);
        sRef[row][er] = refp[(size_t)grow * 8 + er];
    }
    __syncthreads();

    const int w = tid >> 6;
    const int lane = tid & 63;
    const int qs = lane >> 5;
    const int h = (lane >> 2) & 7;
    const int s = lane & 3;
    const int qrow = w * 2 + qs;
    int q = q0 + qrow;
    const bool alive = q < MROWS;
    if (!alive) q = MROWS - 1;
    const int b = (q >= NQ) ? 1 : 0;

    const char* rowp = (const char*)&sOA[qrow][0];
    unsigned off16[16];
    {
        uint4 o0 = *(const uint4*)(rowp + h * 64);
        uint4 o1 = *(const uint4*)(rowp + h * 64 + 16);
        uint4 o2 = *(const uint4*)(rowp + h * 64 + 32);
        uint4 o3 = *(const uint4*)(rowp + h * 64 + 48);
        off16[0]=o0.x; off16[1]=o0.y; off16[2]=o0.z; off16[3]=o0.w;
        off16[4]=o1.x; off16[5]=o1.y; off16[6]=o1.z; off16[7]=o1.w;
        off16[8]=o2.x; off16[9]=o2.y; off16[10]=o2.z; off16[11]=o2.w;
        off16[12]=o3.x; off16[13]=o3.y; off16[14]=o3.z; off16[15]=o3.w;
    }

    float aw[16];
    {
        uint4 g0 = *(const uint4*)(rowp + 512 + h * 32);
        uint4 g1 = *(const uint4*)(rowp + 512 + h * 32 + 16);
        unsigned gu[8] = {g0.x,g0.y,g0.z,g0.w,g1.x,g1.y,g1.z,g1.w};
        float lg[16];
#pragma unroll
        for (int i = 0; i < 8; ++i) {
            f32x2 p = bfpair(gu[i]);
            lg[2*i] = p.x; lg[2*i+1] = p.y;
        }
        float mx = lg[0];
#pragma unroll
        for (int i = 1; i < 16; ++i) mx = fmaxf(mx, lg[i]);
        float ssum = 0.f;
#pragma unroll
        for (int i = 0; i < 16; ++i) { aw[i] = __expf(lg[i] - mx); ssum += aw[i]; }
        float inv = 1.f / ssum;
#pragma unroll
        for (int i = 0; i < 16; ++i) aw[i] *= inv;
    }

    f16x2 acc0 = {0, 0}, acc1 = {0, 0}, acc2 = {0, 0}, acc3 = {0, 0};

#pragma unroll
    for (int l = 0; l < 4; ++l) {
        const int W = LW[l], H = LH[l], Wp = PLW[l];
        const float xb = sRef[qrow][l * 2 + 0] * (float)W + 0.5f;   // pad-coord base
        const float yb = sRef[qrow][l * 2 + 1] * (float)H + 0.5f;
        // head-major: pixel stride is 32 fp16 (64B)
        const _Float16* vl = vproj + ((size_t)(h * 2 + b) * PTOT + PLSTART[l]) * 32 + s * 8;

        // Phase 1: addresses + packed fp16 weights for all 4 taps of this level
        const _Float16* pp[4];
        f16x2 hw[4][4];
#pragma unroll
        for (int p = 0; p < 4; ++p) {
            const int t = l * 4 + p;
            f32x2 o2 = bfpair(off16[t]);
            float x = fminf(fmaxf(xb + o2.x, 0.f), (float)(W + 1));
            float y = fminf(fmaxf(yb + o2.y, 0.f), (float)(H + 1));
            float x0f = floorf(x), y0f = floorf(y);
            float lx = x - x0f, ly = y - y0f;
            int x0 = (int)x0f, y0 = (int)y0f;
            pp[p] = vl + (size_t)((y0 * Wp + x0) * 32);
            float aww = aw[t];
            float wx0 = 1.f - lx;
            float wy0 = (1.f - ly) * aww, wy1 = ly * aww;
            _Float16 h00 = (_Float16)(wx0 * wy0), h01 = (_Float16)(lx * wy0);
            _Float16 h10 = (_Float16)(wx0 * wy1), h11 = (_Float16)(lx * wy1);
            hw[p][0] = f16x2{h00, h00}; hw[p][1] = f16x2{h01, h01};
            hw[p][2] = f16x2{h10, h10}; hw[p][3] = f16x2{h11, h11};
        }

        // Phase 2: issue all 16 gathers (x-pairs are contiguous 128B regions)
        uint4 c[4][4];
#pragma unroll
        for (int p = 0; p < 4; ++p) {
            c[p][0] = *(const uint4*)(pp[p]);
            c[p][1] = *(const uint4*)(pp[p] + 32);
            c[p][2] = *(const uint4*)(pp[p] + Wp * 32);
            c[p][3] = *(const uint4*)(pp[p] + Wp * 32 + 32);
        }

        // Phase 3: packed fp16 FMAs
#pragma unroll
        for (int p = 0; p < 4; ++p)
#pragma unroll
            for (int cc = 0; cc < 4; ++cc) {
                acc0 += __builtin_bit_cast(f16x2, c[p][cc].x) * hw[p][cc];
                acc1 += __builtin_bit_cast(f16x2, c[p][cc].y) * hw[p][cc];
                acc2 += __builtin_bit_cast(f16x2, c[p][cc].z) * hw[p][cc];
                acc3 += __builtin_bit_cast(f16x2, c[p][cc].w) * hw[p][cc];
            }
    }

    if (alive) {
        bf16 ob[8];
        ob[0] = __float2bfloat16((float)acc0[0]);
        ob[1] = __float2bfloat16((float)acc0[1]);
        ob[2] = __float2bfloat16((float)acc1[0]);
        ob[3] = __float2bfloat16((float)acc1[1]);
        ob[4] = __float2bfloat16((float)acc2[0]);
        ob[5] = __float2bfloat16((float)acc2[1]);
        ob[6] = __float2bfloat16((float)acc3[0]);
        ob[7] = __float2bfloat16((float)acc3[1]);
        *(uint4*)(msda_out + (size_t)q * 384 + h * 32 + s * 8) = *(const uint4*)ob;
    }
}

// ---------------------------------------------------------------------------
extern "C" void kernel_launch(void* const* d_in, const int* in_sizes, int n_in,
                              void* d_out, int out_size, void* d_ws, size_t ws_size,
                              hipStream_t stream) {
    const float* query = (const float*)d_in[0];
    const float* value = (const float*)d_in[1];
    const float* refp  = (const float*)d_in[2];
    const float* W_so  = (const float*)d_in[3];
    const float* b_so  = (const float*)d_in[4];
    const float* W_aw  = (const float*)d_in[5];
    const float* b_aw  = (const float*)d_in[6];
    const float* W_vp  = (const float*)d_in[7];
    const float* b_vp  = (const float*)d_in[8];
    const float* W_op  = (const float*)d_in[9];
    const float* b_op  = (const float*)d_in[10];
    float* out = (float*)d_out;

    // Workspace:
    //   offawl : bf16 MROWS*384 (34.1 MB) [off|awl]; msda aliased over rows
    //   vproj  : fp16 16*PTOT*32 (24.3 MB) head-major zero-padded layout
    //   weights: Wt_cat 384*256, Wt_vp/Wt_op 256*256 bf16, bcat 384 f32
    bf16*     d_offawl = (bf16*)d_ws;
    _Float16* d_vproj  = (_Float16*)(d_offawl + (size_t)MROWS * 384);
    bf16*     d_wtcat  = (bf16*)(d_vproj + (size_t)16 * PTOT * 32);
    bf16*     d_wtvp   = d_wtcat + 384 * 256;
    bf16*     d_wtop   = d_wtvp + 256 * 256;
    float*    d_bcat   = (float*)(d_wtop + 256 * 256);

    prep_weights<<<384, 256, 0, stream>>>(W_vp, W_so, W_aw, W_op, b_so, b_aw,
                                          d_wtvp, d_wtcat, d_wtop, d_bcat);
    hipMemsetAsync(d_vproj, 0, (size_t)16 * PTOT * 32 * sizeof(_Float16), stream);

    gemm_producer<<<GX * 5, 256, 0, stream>>>(
        query, value, d_wtcat, d_wtvp, d_bcat, b_vp, d_offawl, d_vproj);

    msda_sample12<<<(MROWS + 7) / 8, 256, 0, stream>>>(
        d_vproj, d_offawl, refp, d_offawl);

    gemm_out<<<GX * 2, 256, 0, stream>>>(d_offawl, d_wtop, b_op, query, out);
}

// Round 14
// 153.017 us; speedup vs baseline: 1.1456x; 1.1130x over previous
//
#include <hip/hip_runtime.h>
#include <hip/hip_bf16.h>
#include <math.h>

typedef __hip_bfloat16 bf16;
using f32x4  = __attribute__((ext_vector_type(4))) float;
using f32x2  = __attribute__((ext_vector_type(2))) float;
using bf16x8 = __attribute__((ext_vector_type(8))) short;
using f16x2  = __attribute__((ext_vector_type(2))) _Float16;

constexpr int BS = 2, NQ = 22223, MROWS = 44446;
constexpr int LH[4] = {100, 50, 25, 13};
constexpr int LW[4] = {167, 84, 42, 21};
constexpr int LSTART[4] = {0, 16700, 20900, 21950};
// Padded levels: +1 left/top, +2 right/bottom (Wp=W+3, Hp=H+3)
constexpr int PLW[4] = {170, 87, 45, 24};
constexpr int PLSTART[4] = {0, 17510, 22121, 23381};
constexpr int PTOT = 23765;

constexpr int BM = 128, BK = 32;
constexpr int LDT = 40;               // LDS row stride (bf16): 80B
constexpr int GX = (MROWS + BM - 1) / BM;   // 348

// ---------------------------------------------------------------------------
__global__ __launch_bounds__(256) void prep_weights(
    const float* __restrict__ W_vp, const float* __restrict__ W_so,
    const float* __restrict__ W_aw, const float* __restrict__ W_op,
    const float* __restrict__ b_so, const float* __restrict__ b_aw,
    bf16* __restrict__ Wt_vp, bf16* __restrict__ Wt_cat,
    bf16* __restrict__ Wt_op, float* __restrict__ bcat)
{
    int i = blockIdx.x * 256 + threadIdx.x;
    if (i < 256 * 256) {
        int n = i >> 8, k = i & 255;
        Wt_vp[i] = __float2bfloat16(W_vp[k * 256 + n]);
        Wt_op[i] = __float2bfloat16(W_op[k * 256 + n]);
    }
    if (i < 384 * 256) {
        int n = i >> 8, k = i & 255;
        float v = (n < 256) ? W_so[k * 256 + n] : W_aw[k * 128 + (n - 256)];
        Wt_cat[i] = __float2bfloat16(v);
    }
    if (i < 384) bcat[i] = (i < 256) ? b_so[i] : b_aw[i - 256];
}

// Map batch-local value pixel -> level-local padded pixel index (+1,+1 offset)
__device__ inline int pad_base_idx(int pix) {
    if (pix < LSTART[1])      { int y = pix / 167;                  int x = pix - y * 167;                return PLSTART[0] + (y + 1) * 170 + (x + 1); }
    else if (pix < LSTART[2]) { int rel = pix - LSTART[1]; int y = rel / 84; int x = rel - y * 84;        return PLSTART[1] + (y + 1) * 87  + (x + 1); }
    else if (pix < LSTART[3]) { int rel = pix - LSTART[2]; int y = rel / 42; int x = rel - y * 42;        return PLSTART[2] + (y + 1) * 45  + (x + 1); }
    else                      { int rel = pix - LSTART[3]; int y = rel / 21; int x = rel - y * 21;        return PLSTART[3] + (y + 1) * 24  + (x + 1); }
}

// ---------------------------------------------------------------------------
// Shared MFMA tile core: acc[4][4] (64x64 per wave) over K=256, BK=32.
// ---------------------------------------------------------------------------
template<bool A_BF16>
__device__ __forceinline__ void mfma_core(
    const void* __restrict__ Av, int lda, const bf16* __restrict__ Wt,
    int row0, int bn0, int M, bf16* As, bf16* Bs, f32x4 (&acc)[4][4])
{
    const int tid = threadIdx.x;
    const int lane = tid & 63;
    const int wv = tid >> 6;
    const int wm = (wv >> 1) * 64, wn = (wv & 1) * 64;
    const int l15 = lane & 15, l4 = lane >> 4;

#pragma unroll
    for (int m = 0; m < 4; ++m)
#pragma unroll
        for (int n = 0; n < 4; ++n) { acc[m][n][0]=0.f; acc[m][n][1]=0.f; acc[m][n][2]=0.f; acc[m][n][3]=0.f; }

    for (int k0 = 0; k0 < 256; k0 += BK) {
        __syncthreads();
#pragma unroll
        for (int t = 0; t < 2; ++t) {
            int idx = tid + t * 256;
            int r = idx >> 2, s = idx & 3;
            {
                int grow = row0 + r; if (grow >= M) grow = M - 1;
                bf16 tmp[8];
                if constexpr (A_BF16) {
                    const bf16* ap = (const bf16*)Av + (size_t)grow * lda + (k0 + s * 8);
                    *(uint4*)tmp = *(const uint4*)ap;
                } else {
                    const float* ap = (const float*)Av + (size_t)grow * lda + (k0 + s * 8);
                    f32x4 v0 = *(const f32x4*)ap;
                    f32x4 v1 = *(const f32x4*)(ap + 4);
#pragma unroll
                    for (int j = 0; j < 4; ++j) tmp[j] = __float2bfloat16(v0[j]);
#pragma unroll
                    for (int j = 0; j < 4; ++j) tmp[4 + j] = __float2bfloat16(v1[j]);
                }
                *(uint4*)&As[r * LDT + s * 8] = *(const uint4*)tmp;
            }
            *(uint4*)&Bs[r * LDT + s * 8] =
                *(const uint4*)(Wt + (size_t)(bn0 + r) * 256 + (k0 + s * 8));
        }
        __syncthreads();

        bf16x8 af[4], bfr[4];
#pragma unroll
        for (int m = 0; m < 4; ++m)
            af[m] = *(const bf16x8*)&As[(wm + m * 16 + l15) * LDT + l4 * 8];
#pragma unroll
        for (int n = 0; n < 4; ++n)
            bfr[n] = *(const bf16x8*)&Bs[(wn + n * 16 + l15) * LDT + l4 * 8];
#pragma unroll
        for (int m = 0; m < 4; ++m)
#pragma unroll
            for (int n = 0; n < 4; ++n)
                acc[m][n] = __builtin_amdgcn_mfma_f32_16x16x32_bf16(af[m], bfr[n], acc[m][n], 0, 0, 0);
    }
}

// ---------------------------------------------------------------------------
// Fused producer GEMM: 5 N-slices per row-panel (3 offawl bf16 + 2 vproj fp16
// head-major scatter), slice-fastest linearization + bijective XCD swizzle.
// vproj layout: [head][batch][padded_pixel][32ch] fp16 (pixel stride 64B).
// ---------------------------------------------------------------------------
__global__ __launch_bounds__(256) void gemm_producer(
    const float* __restrict__ query, const float* __restrict__ value,
    const bf16* __restrict__ Wt_cat, const bf16* __restrict__ Wt_vp,
    const float* __restrict__ bcat, const float* __restrict__ bvp,
    bf16* __restrict__ offawl, _Float16* __restrict__ vproj)
{
    __shared__ bf16 As[BM * LDT];
    __shared__ bf16 Bs[BM * LDT];

    constexpr int NWG = GX * 5;                 // 1740
    constexpr int QXW = NWG / 8, RXW = NWG % 8; // 217, 4
    int orig = blockIdx.x;
    int xcd = orig & 7, seq = orig >> 3;
    int swz = (xcd < RXW ? xcd * (QXW + 1) : RXW * (QXW + 1) + (xcd - RXW) * QXW) + seq;
    int slice = swz % 5;
    int row0 = (swz / 5) * BM;

    const bool isOff = slice < 3;
    const void* A = isOff ? (const void*)query : (const void*)value;
    const bf16* Wt = isOff ? Wt_cat : Wt_vp;
    const float* bias = isOff ? bcat : bvp;
    int bn0 = isOff ? slice * 128 : (slice - 3) * 128;

    f32x4 acc[4][4];
    mfma_core<false>(A, 256, Wt, row0, bn0, MROWS, As, Bs, acc);

    const int lane = threadIdx.x & 63;
    const int wv = threadIdx.x >> 6;
    const int wm = (wv >> 1) * 64, wn = (wv & 1) * 64;
    const int l15 = lane & 15, l4 = lane >> 4;

    if (isOff) {
#pragma unroll
        for (int m = 0; m < 4; ++m)
#pragma unroll
            for (int j = 0; j < 4; ++j) {
                int r = row0 + wm + m * 16 + l4 * 4 + j;
                if (r < MROWS) {
                    bf16* orow = offawl + (size_t)r * 384;
#pragma unroll
                    for (int n = 0; n < 4; ++n) {
                        int fcol = bn0 + wn + n * 16 + l15;
                        orow[fcol] = __float2bfloat16(acc[m][n][j] + bias[fcol]);
                    }
                }
            }
    } else {
#pragma unroll
        for (int m = 0; m < 4; ++m)
#pragma unroll
            for (int j = 0; j < 4; ++j) {
                int r = row0 + wm + m * 16 + l4 * 4 + j;
                if (r < MROWS) {
                    int bb = (r >= NQ) ? 1 : 0;
                    int pb = pad_base_idx(r - bb * NQ);
#pragma unroll
                    for (int n = 0; n < 4; ++n) {
                        int fcol = bn0 + wn + n * 16 + l15;
                        int hh = fcol >> 5, cc = fcol & 31;
                        vproj[((size_t)(hh * 2 + bb) * PTOT + pb) * 32 + cc] =
                            (_Float16)(acc[m][n][j] + bias[fcol]);
                    }
                }
            }
    }
}

// ---------------------------------------------------------------------------
// Output GEMM: out = msda(bf16, ld 384) @ W_op^T + b_op + query.
// ---------------------------------------------------------------------------
__global__ __launch_bounds__(256) void gemm_out(
    const bf16* __restrict__ msda, const bf16* __restrict__ Wt_op,
    const float* __restrict__ b_op, const float* __restrict__ query,
    float* __restrict__ out)
{
    __shared__ bf16 As[BM * LDT];
    __shared__ bf16 Bs[BM * LDT];

    constexpr int NWG = GX * 2;  // 696
    int orig = blockIdx.x;
    int swz = (orig & 7) * (NWG / 8) + (orig >> 3);
    int bn0 = (swz & 1) * 128;
    int row0 = (swz >> 1) * BM;

    f32x4 acc[4][4];
    mfma_core<true>(msda, 384, Wt_op, row0, bn0, MROWS, As, Bs, acc);

    const int lane = threadIdx.x & 63;
    const int wv = threadIdx.x >> 6;
    const int wm = (wv >> 1) * 64, wn = (wv & 1) * 64;
    const int l15 = lane & 15, l4 = lane >> 4;

#pragma unroll
    for (int m = 0; m < 4; ++m)
#pragma unroll
        for (int j = 0; j < 4; ++j) {
            int r = row0 + wm + m * 16 + l4 * 4 + j;
            if (r < MROWS) {
#pragma unroll
                for (int n = 0; n < 4; ++n) {
                    int fcol = bn0 + wn + n * 16 + l15;
                    out[(size_t)r * 256 + fcol] =
                        acc[m][n][j] + b_op[fcol] + query[(size_t)r * 256 + fcol];
                }
            }
        }
}

// ---------------------------------------------------------------------------
// MSDA sampling v14: 1 query per WAVE, 8 lanes per (q,h).
// lane = h*8 + s ; sx = s>>2 picks x-corner column, c16 = s&3 picks the 16B
// channel chunk. Head-major pixels are 64B, so the (x0,x1) corner pair is a
// contiguous 128B segment covered by the 8 lanes in ONE load instruction per
// tap-row (2 loads/lane/tap vs 4 before). Each lane applies its x-side
// weight; x-sides are summed at the end via __shfl_xor(.,4) packed adds.
// Per-level batch: 8 loads/lane = 32 dest VGPRs -> survives allocation.
// ---------------------------------------------------------------------------
__device__ inline f32x2 bfpair(unsigned u) {
    f32x2 r;
    r.x = __uint_as_float(u << 16);
    r.y = __uint_as_float(u & 0xffff0000u);
    return r;
}

__global__ __launch_bounds__(256)
__attribute__((amdgpu_waves_per_eu(2, 4)))
void msda_sample14(
    const _Float16* __restrict__ vproj,  // [head][batch][ppix][32] fp16
    const bf16* __restrict__ offawl,     // [MROWS][384] bf16
    const float* __restrict__ refp,
    bf16* __restrict__ msda_out)         // aliases offawl rows (stride 384)
{
    __shared__ uint2 sOA[4][96];         // 4 rows x 768B
    __shared__ float sRef[4][8];

    // bijective XCD swizzle (NBLK % 8 == 0 -> simple form)
    constexpr int NBLK = (MROWS + 3) / 4;        // 11112
    const int orig = blockIdx.x;
    const int blk = (orig & 7) * (NBLK / 8) + (orig >> 3);
    const int q0 = blk * 4;

    const int tid = threadIdx.x;

#pragma unroll
    for (int k = 0; k < 2; ++k) {
        int idx = tid + k * 256;
        if (idx < 384) {
            int row = idx / 96, e = idx - (idx / 96) * 96;
            int grow = min(q0 + row, MROWS - 1);
            sOA[row][e] = *((const uint2*)(offawl + (size_t)grow * 384) + e);
        }
    }
    if (tid < 32) {
        int row = tid >> 3, er = tid & 7;
        int grow = min(q0 + row, MROWS - 1);
        sRef[row][er] = refp[(size_t)grow * 8 + er];
    }
    __syncthreads();

    const int w = tid >> 6;       // wave id == query slot
    const int lane = tid & 63;
    const int h = lane >> 3;
    const int s = lane & 7;
    const int sx = s >> 2;        // x-corner side (0 -> x0, 1 -> x1)
    const int c16 = s & 3;        // 16B channel chunk
    int q = q0 + w;
    const bool alive = q < MROWS;
    if (!alive) q = MROWS - 1;
    const int b = (q >= NQ) ? 1 : 0;

    const char* rowp = (const char*)&sOA[w][0];

    // per-head softmax over 16 logits (redundant across the 8 lanes)
    float aw[16];
    {
        uint4 g0 = *(const uint4*)(rowp + 512 + h * 32);
        uint4 g1 = *(const uint4*)(rowp + 512 + h * 32 + 16);
        unsigned gu[8] = {g0.x,g0.y,g0.z,g0.w,g1.x,g1.y,g1.z,g1.w};
        float lg[16];
#pragma unroll
        for (int i = 0; i < 8; ++i) {
            f32x2 p = bfpair(gu[i]);
            lg[2*i] = p.x; lg[2*i+1] = p.y;
        }
        float mx = lg[0];
#pragma unroll
        for (int i = 1; i < 16; ++i) mx = fmaxf(mx, lg[i]);
        float ssum = 0.f;
#pragma unroll
        for (int i = 0; i < 16; ++i) { aw[i] = __expf(lg[i] - mx); ssum += aw[i]; }
        float inv = 1.f / ssum;
#pragma unroll
        for (int i = 0; i < 16; ++i) aw[i] *= inv;
    }

    f16x2 acc0 = {0, 0}, acc1 = {0, 0}, acc2 = {0, 0}, acc3 = {0, 0};

#pragma unroll
    for (int l = 0; l < 4; ++l) {
        const int W = LW[l], H = LH[l], Wp = PLW[l];
        const float xb = sRef[w][l * 2 + 0] * (float)W + 0.5f;   // pad-coord base
        const float yb = sRef[w][l * 2 + 1] * (float)H + 0.5f;
        // head-major: pixel stride 32 fp16 (64B); this lane covers chunk c16
        const _Float16* vl = vproj + ((size_t)(h * 2 + b) * PTOT + PLSTART[l]) * 32 + c16 * 8;

        // Phase 1: addresses + per-lane (x-side) weights for 4 taps
        const _Float16* pr[4][2];
        f16x2 hwv[4][2];
#pragma unroll
        for (int p = 0; p < 4; ++p) {
            unsigned ov = *(const unsigned*)(rowp + h * 64 + (l * 4 + p) * 4);
            f32x2 o2 = bfpair(ov);
            float x = fminf(fmaxf(xb + o2.x, 0.f), (float)(W + 1));
            float y = fminf(fmaxf(yb + o2.y, 0.f), (float)(H + 1));
            float x0f = floorf(x), y0f = floorf(y);
            float lx = x - x0f, ly = y - y0f;
            int x0 = (int)x0f, y0 = (int)y0f;
            pr[p][0] = vl + (size_t)((y0 * Wp + x0 + sx) * 32);
            pr[p][1] = pr[p][0] + Wp * 32;
            float wxs = sx ? lx : (1.f - lx);
            float a = aw[l * 4 + p];
            _Float16 e0 = (_Float16)(wxs * (1.f - ly) * a);
            _Float16 e1 = (_Float16)(wxs * ly * a);
            hwv[p][0] = f16x2{e0, e0};
            hwv[p][1] = f16x2{e1, e1};
        }

        // Phase 2: 8 loads in flight (each is 1/8 of a coalesced 128B segment)
        uint4 c[4][2];
#pragma unroll
        for (int p = 0; p < 4; ++p) {
            c[p][0] = *(const uint4*)pr[p][0];
            c[p][1] = *(const uint4*)pr[p][1];
        }

        // Phase 3: packed fp16 FMAs (4 per load)
#pragma unroll
        for (int p = 0; p < 4; ++p)
#pragma unroll
            for (int r = 0; r < 2; ++r) {
                acc0 += __builtin_bit_cast(f16x2, c[p][r].x) * hwv[p][r];
                acc1 += __builtin_bit_cast(f16x2, c[p][r].y) * hwv[p][r];
                acc2 += __builtin_bit_cast(f16x2, c[p][r].z) * hwv[p][r];
                acc3 += __builtin_bit_cast(f16x2, c[p][r].w) * hwv[p][r];
            }
    }

    // combine x0/x1 partial sums across lane pairs (s ^ 4)
    {
        unsigned u0 = __builtin_bit_cast(unsigned, acc0);
        unsigned u1 = __builtin_bit_cast(unsigned, acc1);
        unsigned u2 = __builtin_bit_cast(unsigned, acc2);
        unsigned u3 = __builtin_bit_cast(unsigned, acc3);
        acc0 += __builtin_bit_cast(f16x2, __shfl_xor((int)u0, 4));
        acc1 += __builtin_bit_cast(f16x2, __shfl_xor((int)u1, 4));
        acc2 += __builtin_bit_cast(f16x2, __shfl_xor((int)u2, 4));
        acc3 += __builtin_bit_cast(f16x2, __shfl_xor((int)u3, 4));
    }

    if (alive && sx == 0) {
        bf16 ob[8];
        ob[0] = __float2bfloat16((float)acc0[0]);
        ob[1] = __float2bfloat16((float)acc0[1]);
        ob[2] = __float2bfloat16((float)acc1[0]);
        ob[3] = __float2bfloat16((float)acc1[1]);
        ob[4] = __float2bfloat16((float)acc2[0]);
        ob[5] = __float2bfloat16((float)acc2[1]);
        ob[6] = __float2bfloat16((float)acc3[0]);
        ob[7] = __float2bfloat16((float)acc3[1]);
        *(uint4*)(msda_out + (size_t)q * 384 + h * 32 + c16 * 8) = *(const uint4*)ob;
    }
}

// ---------------------------------------------------------------------------
extern "C" void kernel_launch(void* const* d_in, const int* in_sizes, int n_in,
                              void* d_out, int out_size, void* d_ws, size_t ws_size,
                              hipStream_t stream) {
    const float* query = (const float*)d_in[0];
    const float* value = (const float*)d_in[1];
    const float* refp  = (const float*)d_in[2];
    const float* W_so  = (const float*)d_in[3];
    const float* b_so  = (const float*)d_in[4];
    const float* W_aw  = (const float*)d_in[5];
    const float* b_aw  = (const float*)d_in[6];
    const float* W_vp  = (const float*)d_in[7];
    const float* b_vp  = (const float*)d_in[8];
    const float* W_op  = (const float*)d_in[9];
    const float* b_op  = (const float*)d_in[10];
    float* out = (float*)d_out;

    // Workspace:
    //   offawl : bf16 MROWS*384 (34.1 MB) [off|awl]; msda aliased over rows
    //   vproj  : fp16 16*PTOT*32 (24.3 MB) head-major zero-padded layout
    //   weights: Wt_cat 384*256, Wt_vp/Wt_op 256*256 bf16, bcat 384 f32
    bf16*     d_offawl = (bf16*)d_ws;
    _Float16* d_vproj  = (_Float16*)(d_offawl + (size_t)MROWS * 384);
    bf16*     d_wtcat  = (bf16*)(d_vproj + (size_t)16 * PTOT * 32);
    bf16*     d_wtvp   = d_wtcat + 384 * 256;
    bf16*     d_wtop   = d_wtvp + 256 * 256;
    float*    d_bcat   = (float*)(d_wtop + 256 * 256);

    prep_weights<<<384, 256, 0, stream>>>(W_vp, W_so, W_aw, W_op, b_so, b_aw,
                                          d_wtvp, d_wtcat, d_wtop, d_bcat);
    hipMemsetAsync(d_vproj, 0, (size_t)16 * PTOT * 32 * sizeof(_Float16), stream);

    gemm_producer<<<GX * 5, 256, 0, stream>>>(
        query, value, d_wtcat, d_wtvp, d_bcat, b_vp, d_offawl, d_vproj);

    msda_sample14<<<(MROWS + 3) / 4, 256, 0, stream>>>(
        d_vproj, d_offawl, refp, d_offawl);

    gemm_out<<<GX * 2, 256, 0, stream>>>(d_offawl, d_wtop, b_op, query, out);
}